// Round 11
// baseline (313.923 us; speedup 1.0000x reference)
//
#include <hip/hip_runtime.h>
#include <hip/hip_bf16.h>

// WindowAttention v11: barrier-free qkv (W direct global->VGPR, zero LDS,
// zero syncthreads) + r10 attn (GLOAD k/v deep queue) at 5 blocks/CU.
// N=128 tokens, B_=1024 windows, C=192, H=6, hd=32.
// ws: bmF f32 [6*64][16384] ((bias+mask)*LOG2E, r6 frag order) |
//     wbf bf16[576][192] LINEAR | pwbf linear |
//     q bf16 [b][h][128][32] linear, pre-scaled SCALE*LOG2E |
//     k swz (short col ^ ((tok>>1)&3)<<3 within 32-short row) |
//     v^T swz (short col ^ (d&15)<<3 within 128-short row)
// attn bf16 out in d_out slot: d_out + b*98304 + 49152 (block-private).

typedef float f32x4 __attribute__((ext_vector_type(4)));
typedef short short8 __attribute__((ext_vector_type(8)));
typedef short short4e __attribute__((ext_vector_type(4)));

#define SCALE 0.17677669529663687f
#define LOG2E 1.4426950408889634f
#define QSC (SCALE * LOG2E)

#define GLOAD16(src, dst)                                                      \
  __builtin_amdgcn_global_load_lds(                                            \
      (const __attribute__((address_space(1))) unsigned int*)(const void*)(src),\
      (__attribute__((address_space(3))) unsigned int*)(void*)(dst), 16, 0, 0)

static __device__ __forceinline__ short f2bf(float f) {
  __hip_bfloat16 h = __float2bfloat16(f);
  return __builtin_bit_cast(short, h);
}
static __device__ __forceinline__ f32x4 mfma16(short8 a, short8 b, f32x4 c) {
  return __builtin_amdgcn_mfma_f32_16x16x32_bf16(a, b, c, 0, 0, 0);
}

// ---------------- prep: qkv_w/proj_w -> bf16 (both linear) ----------------
__global__ __launch_bounds__(256) void prep_w(const float* __restrict__ qkvw,
                                              const float* __restrict__ projw,
                                              short* __restrict__ wbf,
                                              short* __restrict__ pwbf) {
  int t = blockIdx.x * 256 + threadIdx.x;  // float4 index 0..36863
  const int NQ = 27648;                    // 576*192/4
  float4 f; short* dst;
  if (t < NQ) { f = ((const float4*)qkvw)[t]; dst = wbf + t * 4; }
  else        { f = ((const float4*)projw)[t - NQ]; dst = pwbf + (t - NQ) * 4; }
  short4e o; o[0] = f2bf(f.x); o[1] = f2bf(f.y); o[2] = f2bf(f.z); o[3] = f2bf(f.w);
  *(short4e*)dst = o;
}

// ---------------- prep_bm: (bias+mask)*LOG2E tiles, r6 fragment layout ----------------
__global__ __launch_bounds__(256) void prep_bm(const int* __restrict__ rel,
                                               const float* __restrict__ table,
                                               const float* __restrict__ mask,
                                               float* __restrict__ bmF) {
  int blk = blockIdx.x;            // 384 blocks: h*64 + w
  int h = blk >> 6, w = blk & 63;
  int tid = threadIdx.x, lane = tid & 63, wave = tid >> 6;
  int lr = lane & 15, r4 = (lane >> 4) * 4;
  const float* mk = mask + (size_t)w * 16384;
  float* dst = bmF + (size_t)blk * 16384;
#pragma unroll
  for (int L = 0; L < 16; ++L) {
    int rf = L >> 3, rg = (L >> 1) & 3, cp = L & 1;
    int row = wave * 32 + rf * 16 + r4 + rg;
    float4 v;
#pragma unroll
    for (int e = 0; e < 4; ++e) {
      int col = (cp * 4 + e) * 16 + lr;
      float bias = table[rel[row * 128 + col] * 6 + h];
      ((float*)&v)[e] = (bias + mk[row * 128 + col]) * LOG2E;
    }
    ((float4*)dst)[L * 256 + tid] = v;
  }
}

// ---------------- qkv: x in regs, W direct from global, NO LDS / NO barriers ----------------
__global__ __launch_bounds__(256, 3) void qkv_kernel(const float* __restrict__ x,
                                                     const short* __restrict__ wbf,
                                                     short* __restrict__ qb,
                                                     short* __restrict__ kb,
                                                     short* __restrict__ vb) {
  const int b = blockIdx.x, tid = threadIdx.x;
  const int wave = tid >> 6, lane = tid & 63;
  const int lr = lane & 15, g = lane >> 4, g8 = g * 8, r4 = g * 4;
  const int rowbase = wave * 32;

  // x -> fragments: rows rowbase+tf*16+lr, kdim g*8..
  short8 xa[2][6];
  {
    const float* xr = x + (size_t)b * 24576 + (size_t)(rowbase + lr) * 192;
#pragma unroll
    for (int tf = 0; tf < 2; ++tf)
#pragma unroll
      for (int ks = 0; ks < 6; ++ks) {
        const float* p = xr + tf * 16 * 192 + ks * 32 + g8;
        float4 f0 = *(const float4*)p;
        float4 f1 = *(const float4*)(p + 4);
        short8 v8;
        v8[0] = f2bf(f0.x); v8[1] = f2bf(f0.y); v8[2] = f2bf(f0.z); v8[3] = f2bf(f0.w);
        v8[4] = f2bf(f1.x); v8[5] = f2bf(f1.y); v8[6] = f2bf(f1.z); v8[7] = f2bf(f1.w);
        xa[tf][ks] = v8;
      }
  }

  // W fragment base pointers (lane-indexed; identical across waves -> L1-hot)
  const short* w0p = wbf + lr * 192 + g8;         // rows lr of each chunk
  const short* w1p = wbf + (16 + lr) * 192 + g8;  // rows 16+lr

#pragma unroll
  for (int ch = 0; ch < 18; ++ch) {
    short8 w0[6], w1[6];
#pragma unroll
    for (int ks = 0; ks < 6; ++ks) {
      w0[ks] = *(const short8*)(w0p + ch * 6144 + ks * 32);
      w1[ks] = *(const short8*)(w1p + ch * 6144 + ks * 32);
    }
    f32x4 acc[2][2];
    acc[0][0] = acc[0][1] = acc[1][0] = acc[1][1] = f32x4{0.f, 0.f, 0.f, 0.f};
    if (ch < 12) {
      // swapped MFMA: D[wcol][tok]
      __builtin_amdgcn_s_setprio(1);
#pragma unroll
      for (int ks = 0; ks < 6; ++ks) {
        acc[0][0] = mfma16(w0[ks], xa[0][ks], acc[0][0]);
        acc[0][1] = mfma16(w0[ks], xa[1][ks], acc[0][1]);
        acc[1][0] = mfma16(w1[ks], xa[0][ks], acc[1][0]);
        acc[1][1] = mfma16(w1[ks], xa[1][ks], acc[1][1]);
      }
      __builtin_amdgcn_s_setprio(0);
      const bool isq = (ch < 6);
      short* dst = isq ? qb : kb;
      const int h = isq ? ch : ch - 6;
      const float sc = isq ? QSC : 1.0f;
      size_t base = ((size_t)b * 6 + h) * 4096;
#pragma unroll
      for (int cf = 0; cf < 2; ++cf)
#pragma unroll
        for (int tf = 0; tf < 2; ++tf) {
          int tok = rowbase + tf * 16 + lr;
          int col = cf * 16 + r4;
          int idx = isq ? col : (col ^ (((tok >> 1) & 3) << 3));
          short4e s4;
          s4[0] = f2bf(acc[cf][tf][0] * sc);
          s4[1] = f2bf(acc[cf][tf][1] * sc);
          s4[2] = f2bf(acc[cf][tf][2] * sc);
          s4[3] = f2bf(acc[cf][tf][3] * sc);
          *(short4e*)&dst[base + (size_t)tok * 32 + idx] = s4;
        }
    } else {
      // non-swapped: D[tok][wcol] -> v^T swizzled stores
      __builtin_amdgcn_s_setprio(1);
#pragma unroll
      for (int ks = 0; ks < 6; ++ks) {
        acc[0][0] = mfma16(xa[0][ks], w0[ks], acc[0][0]);
        acc[0][1] = mfma16(xa[0][ks], w1[ks], acc[0][1]);
        acc[1][0] = mfma16(xa[1][ks], w0[ks], acc[1][0]);
        acc[1][1] = mfma16(xa[1][ks], w1[ks], acc[1][1]);
      }
      __builtin_amdgcn_s_setprio(0);
      const int h = ch - 12;
      size_t base = ((size_t)b * 6 + h) * 4096;
#pragma unroll
      for (int tf = 0; tf < 2; ++tf)
#pragma unroll
        for (int cf = 0; cf < 2; ++cf) {
          int d = cf * 16 + lr;
          int rowpos = rowbase + tf * 16 + r4;
          short4e s4;
          s4[0] = f2bf(acc[tf][cf][0]);
          s4[1] = f2bf(acc[tf][cf][1]);
          s4[2] = f2bf(acc[tf][cf][2]);
          s4[3] = f2bf(acc[tf][cf][3]);
          *(short4e*)&vb[base + (size_t)d * 128 + (rowpos ^ ((d & 15) << 3))] = s4;
        }
    }
  }
}

// ---------------- attn per (window,head): GLOAD k/v, q direct, 32KB LDS ----------------
__global__ __launch_bounds__(256, 5) void attn_kernel(const short* __restrict__ qb,
                                                      const short* __restrict__ kb,
                                                      const short* __restrict__ vb,
                                                      const float* __restrict__ bmF,
                                                      char* __restrict__ outc) {
  __shared__ char sbuf[16384];   // k 8KB | v 8KB (swizzled images)
  __shared__ short p_lds[8192];  // 4 waves x 4KB P scratch
  const int bh = blockIdx.x, b = bh / 6, h = bh - b * 6;
  const short* qt = qb + (size_t)bh * 4096;
  const char* kc = (const char*)(kb + (size_t)bh * 4096);
  const char* vc = (const char*)(vb + (size_t)bh * 4096);
  const float4* bm4 = (const float4*)(bmF + ((size_t)h * 64 + (b & 63)) * 16384);
  short* outSlot = (short*)(outc + (size_t)b * 98304 + 49152);
  const int tid = threadIdx.x, wave = tid >> 6, lane = tid & 63;
  const int lr = lane & 15, g = lane >> 4, r4 = g * 4;
  const int rowbase = wave * 32;
  const int wl = wave * 1024 + lane * 16;
  const int wu = wave * 1024;

  // deep-queue stage: k,v 16KB via 4 global_load_lds per thread
  GLOAD16(kc + wl,        sbuf + wu);
  GLOAD16(kc + 4096 + wl, sbuf + 4096 + wu);
  GLOAD16(vc + wl,        sbuf + 8192 + wu);
  GLOAD16(vc + 4096 + wl, sbuf + 12288 + wu);
  // q: wave-private rows, direct global->reg (coalesced), independent of LDS
  short8 qaH[2];
  qaH[0] = *(const short8*)&qt[(rowbase + lr) * 32 + g * 8];
  qaH[1] = *(const short8*)&qt[(rowbase + 16 + lr) * 32 + g * 8];
  __syncthreads();

  const char* ksb = sbuf;
  const char* vs = sbuf + 8192;
  char* pw = (char*)p_lds + wave * 4096;
  const int kkey = ((lr >> 1) & 3) << 4;  // k-row swizzle key (krow>>1)&3 == (lr>>1)&3

#pragma unroll
  for (int rf = 0; rf < 2; ++rf) {
    // prefetch bias+mask fragments for this rf (8 x 16B)
    float4 bmv[8];
#pragma unroll
    for (int i = 0; i < 8; ++i) bmv[i] = bm4[(rf * 8 + i) * 256 + tid];
    short8 qa = qaH[rf];
    f32x4 s[8];
    __builtin_amdgcn_s_setprio(1);
#pragma unroll
    for (int cf = 0; cf < 8; ++cf) {
      int krow = cf * 16 + lr;
      short8 kf = *(const short8*)(ksb + krow * 64 + ((g * 16) ^ kkey));
      f32x4 z = {0.f, 0.f, 0.f, 0.f};
      s[cf] = mfma16(qa, kf, z);
    }
    __builtin_amdgcn_s_setprio(0);
    float inv_[4];
#pragma unroll
    for (int rg = 0; rg < 4; ++rg) {
      float4 bb0 = bmv[rg * 2];
      float4 bb1 = bmv[rg * 2 + 1];
      float p0 = exp2f(s[0][rg] + bb0.x);
      float p1 = exp2f(s[1][rg] + bb0.y);
      float p2 = exp2f(s[2][rg] + bb0.z);
      float p3 = exp2f(s[3][rg] + bb0.w);
      float p4 = exp2f(s[4][rg] + bb1.x);
      float p5 = exp2f(s[5][rg] + bb1.y);
      float p6 = exp2f(s[6][rg] + bb1.z);
      float p7 = exp2f(s[7][rg] + bb1.w);
      float sum = ((p0 + p1) + (p2 + p3)) + ((p4 + p5) + (p6 + p7));
#pragma unroll
      for (int o = 1; o < 16; o <<= 1) sum += __shfl_xor(sum, o);
      inv_[rg] = 1.0f / sum;
      int rr = r4 + rg;                 // row within this rf's 16
      int base = rr * 256 + (lr << 1);
      int swz = rr << 4;
      *(short*)(pw + ((base + 0 * 32) ^ swz)) = f2bf(p0);
      *(short*)(pw + ((base + 1 * 32) ^ swz)) = f2bf(p1);
      *(short*)(pw + ((base + 2 * 32) ^ swz)) = f2bf(p2);
      *(short*)(pw + ((base + 3 * 32) ^ swz)) = f2bf(p3);
      *(short*)(pw + ((base + 4 * 32) ^ swz)) = f2bf(p4);
      *(short*)(pw + ((base + 5 * 32) ^ swz)) = f2bf(p5);
      *(short*)(pw + ((base + 6 * 32) ^ swz)) = f2bf(p6);
      *(short*)(pw + ((base + 7 * 32) ^ swz)) = f2bf(p7);
    }
    // PV: D[qtok][d]; P (wave-private) + V from LDS, no barrier
    f32x4 o0 = {0.f, 0.f, 0.f, 0.f}, o1 = {0.f, 0.f, 0.f, 0.f};
#pragma unroll
    for (int kst = 0; kst < 4; ++kst) {
      short8 pa = *(const short8*)(pw + ((lr * 256 + kst * 64 + g * 16) ^ (lr << 4)));
      short8 vb0 = *(const short8*)(vs + ((lr * 256 + kst * 64 + g * 16) ^ ((lr & 15) << 4)));
      short8 vb1 = *(const short8*)(vs + (((16 + lr) * 256 + kst * 64 + g * 16) ^ (((16 + lr) & 15) << 4)));
      __builtin_amdgcn_s_setprio(1);
      o0 = mfma16(pa, vb0, o0);
      o1 = mfma16(pa, vb1, o1);
      __builtin_amdgcn_s_setprio(0);
    }
    // epilogue (round-6 proven scalar form)
#pragma unroll
    for (int rg = 0; rg < 4; ++rg) {
      int tok = rowbase + rf * 16 + r4 + rg;
      float iv = inv_[rg];
      outSlot[(size_t)tok * 192 + h * 32 + lr] = f2bf(o0[rg] * iv);
      outSlot[(size_t)tok * 192 + h * 32 + 16 + lr] = f2bf(o1[rg] * iv);
    }
  }
}

// ---------------- proj: ain[128][192] (bf16 in own d_out slot) @ proj_w^T + b ----------------
__global__ __launch_bounds__(256, 2) void proj_kernel(const short* __restrict__ pwbf,
                                                      const float* __restrict__ pb,
                                                      float* __restrict__ out) {
  __shared__ short at[24576];
  __shared__ short wt[2][6144];
  const int b = blockIdx.x, tid = threadIdx.x;
  const int wave = tid >> 6, lane = tid & 63;
  const int lr = lane & 15, g = lane >> 4;
  const int g16 = g * 16, r4 = g * 4;
  const int rowbase = wave * 32;
  const int xorkey = (lr & 7) << 4;
  char* atb = (char*)at;
  char* wtb = (char*)wt;

  int wsoff[3], wdoff[3];
#pragma unroll
  for (int i = 0; i < 3; ++i) {
    int idx8 = i * 256 + tid;
    int r = idx8 / 24, c = idx8 - r * 24;
    wsoff[i] = idx8 * 8;
    wdoff[i] = r * 384 + ((c * 16) ^ ((r & 7) << 4));
  }
  short8 wreg[3];
#pragma unroll
  for (int i = 0; i < 3; ++i) wreg[i] = *(const short8*)(pwbf + wsoff[i]);

  const short8* ar = (const short8*)((const char*)out + (size_t)b * 98304 + 49152);
#pragma unroll
  for (int i = 0; i < 12; ++i) {
    int idx8 = i * 256 + tid;
    int r = idx8 / 24, c = idx8 - r * 24;
    short8 v = ar[idx8];
    *(short8*)(atb + r * 384 + ((c * 16) ^ ((r & 7) << 4))) = v;
  }
#pragma unroll
  for (int i = 0; i < 3; ++i) *(short8*)(wtb + wdoff[i]) = wreg[i];
  __syncthreads();

  const int rA0 = (rowbase + lr) * 384, rA1 = rA0 + 16 * 384;
  const int wB0 = lr * 384, wB1 = wB0 + 16 * 384;

  for (int ch = 0; ch < 6; ++ch) {
    if (ch < 5) {
#pragma unroll
      for (int i = 0; i < 3; ++i)
        wreg[i] = *(const short8*)(pwbf + (ch + 1) * 6144 + wsoff[i]);
    }
    const char* wbuf = wtb + (ch & 1) * 12288;
    f32x4 acc[2][2];
    acc[0][0] = acc[0][1] = acc[1][0] = acc[1][1] = f32x4{0.f, 0.f, 0.f, 0.f};
#pragma unroll
    for (int ks = 0; ks < 6; ++ks) {
      int cx = (ks * 64 + g16) ^ xorkey;
      short8 xa0 = *(const short8*)(atb + rA0 + cx);
      short8 xa1 = *(const short8*)(atb + rA1 + cx);
      short8 wf0 = *(const short8*)(wbuf + wB0 + cx);
      short8 wf1 = *(const short8*)(wbuf + wB1 + cx);
      acc[0][0] = mfma16(xa0, wf0, acc[0][0]);
      acc[0][1] = mfma16(xa0, wf1, acc[0][1]);
      acc[1][0] = mfma16(xa1, wf0, acc[1][0]);
      acc[1][1] = mfma16(xa1, wf1, acc[1][1]);
    }
#pragma unroll
    for (int cf = 0; cf < 2; ++cf) {
      int j = ch * 32 + cf * 16 + lr;
      float bj = pb[j];
#pragma unroll
      for (int rf = 0; rf < 2; ++rf)
#pragma unroll
        for (int rg = 0; rg < 4; ++rg) {
          int tok = rowbase + rf * 16 + r4 + rg;
          out[((size_t)b * 128 + tok) * 192 + j] = acc[rf][cf][rg] + bj;
        }
    }
    if (ch < 5) {
#pragma unroll
      for (int i = 0; i < 3; ++i)
        *(short8*)(wtb + ((ch + 1) & 1) * 12288 + wdoff[i]) = wreg[i];
      __syncthreads();
    }
  }
}

extern "C" void kernel_launch(void* const* d_in, const int* in_sizes, int n_in,
                              void* d_out, int out_size, void* d_ws, size_t ws_size,
                              hipStream_t stream) {
  const float* x      = (const float*)d_in[0];
  const float* mask   = (const float*)d_in[1];
  const float* qkv_w  = (const float*)d_in[2];
  const float* proj_w = (const float*)d_in[3];
  const float* proj_b = (const float*)d_in[4];
  const float* table  = (const float*)d_in[5];
  const int*   rel    = (const int*)d_in[6];
  char* ws = (char*)d_ws;
  size_t o = 0;
  float* bmF  = (float*)(ws + o); o += 25165824;   // 384 * 16384 * 4
  short* wbf  = (short*)(ws + o); o += 221184;
  short* pwbf = (short*)(ws + o); o += 73728;
  short* qbp  = (short*)(ws + o); o += 50331648;
  short* kbp  = (short*)(ws + o); o += 50331648;
  short* vbp  = (short*)(ws + o); o += 50331648;
  float* out = (float*)d_out;

  prep_w<<<144, 256, 0, stream>>>(qkv_w, proj_w, wbf, pwbf);
  prep_bm<<<384, 256, 0, stream>>>(rel, table, mask, bmF);
  qkv_kernel<<<1024, 256, 0, stream>>>(x, wbf, qbp, kbp, vbp);
  attn_kernel<<<6144, 256, 0, stream>>>(qbp, kbp, vbp, bmF, (char*)d_out);
  proj_kernel<<<1024, 256, 0, stream>>>(pwbf, proj_b, (float*)d_out);
}

// Round 12
// 251.011 us; speedup vs baseline: 1.2506x; 1.2506x over previous
//
#include <hip/hip_runtime.h>
#include <hip/hip_bf16.h>

// WindowAttention v12: r10 pipeline; qkv chunk width 32->64 (barriers 17->8,
// 48KB LDS dbuf, 3 blk/CU) + attn at 5 blk/CU. All swizzles r10-proven.
// N=128 tokens, B_=1024 windows, C=192, H=6, hd=32.
// ws: bmF f32 [6*64][16384] ((bias+mask)*LOG2E, r6 frag order) |
//     wbf bf16[576][192] GLOBAL-SWIZZLED (short col ^ (row&7)<<3) | pwbf linear |
//     q bf16 [b][h][128][32] linear, pre-scaled SCALE*LOG2E |
//     k swz (short col ^ ((tok>>1)&3)<<3) | v^T swz (short col ^ (d&15)<<3)
// attn bf16 out in d_out slot: d_out + b*98304 + 49152 (block-private).

typedef float f32x4 __attribute__((ext_vector_type(4)));
typedef short short8 __attribute__((ext_vector_type(8)));
typedef short short4e __attribute__((ext_vector_type(4)));

#define SCALE 0.17677669529663687f
#define LOG2E 1.4426950408889634f
#define QSC (SCALE * LOG2E)

#define GLOAD16(src, dst)                                                      \
  __builtin_amdgcn_global_load_lds(                                            \
      (const __attribute__((address_space(1))) unsigned int*)(const void*)(src),\
      (__attribute__((address_space(3))) unsigned int*)(void*)(dst), 16, 0, 0)

static __device__ __forceinline__ short f2bf(float f) {
  __hip_bfloat16 h = __float2bfloat16(f);
  return __builtin_bit_cast(short, h);
}
static __device__ __forceinline__ f32x4 mfma16(short8 a, short8 b, f32x4 c) {
  return __builtin_amdgcn_mfma_f32_16x16x32_bf16(a, b, c, 0, 0, 0);
}

// ---------------- prep: qkv_w -> bf16 swizzled, proj_w -> bf16 linear ----------------
__global__ __launch_bounds__(256) void prep_w(const float* __restrict__ qkvw,
                                              const float* __restrict__ projw,
                                              short* __restrict__ wbf,
                                              short* __restrict__ pwbf) {
  int t = blockIdx.x * 256 + threadIdx.x;  // float4 index 0..36863
  const int NQ = 27648;                    // 576*192/4
  float4 f; short* dst;
  if (t < NQ) {
    f = ((const float4*)qkvw)[t];
    int row = (t * 4) / 192, c4 = (t * 4) % 192;
    dst = wbf + row * 192 + (c4 ^ ((row & 7) << 3));  // row-local swizzle
  } else {
    f = ((const float4*)projw)[t - NQ];
    dst = pwbf + (t - NQ) * 4;
  }
  short4e o; o[0] = f2bf(f.x); o[1] = f2bf(f.y); o[2] = f2bf(f.z); o[3] = f2bf(f.w);
  *(short4e*)dst = o;
}

// ---------------- prep_bm: (bias+mask)*LOG2E tiles, r6 fragment layout ----------------
__global__ __launch_bounds__(256) void prep_bm(const int* __restrict__ rel,
                                               const float* __restrict__ table,
                                               const float* __restrict__ mask,
                                               float* __restrict__ bmF) {
  int blk = blockIdx.x;            // 384 blocks: h*64 + w
  int h = blk >> 6, w = blk & 63;
  int tid = threadIdx.x, lane = tid & 63, wave = tid >> 6;
  int lr = lane & 15, r4 = (lane >> 4) * 4;
  const float* mk = mask + (size_t)w * 16384;
  float* dst = bmF + (size_t)blk * 16384;
#pragma unroll
  for (int L = 0; L < 16; ++L) {
    int rf = L >> 3, rg = (L >> 1) & 3, cp = L & 1;
    int row = wave * 32 + rf * 16 + r4 + rg;
    float4 v;
#pragma unroll
    for (int e = 0; e < 4; ++e) {
      int col = (cp * 4 + e) * 16 + lr;
      float bias = table[rel[row * 128 + col] * 6 + h];
      ((float*)&v)[e] = (bias + mk[row * 128 + col]) * LOG2E;
    }
    ((float4*)dst)[L * 256 + tid] = v;
  }
}

// ---------------- qkv: x in regs, W via GLOAD 64-col chunks (9 chunks, 8 barriers) ----------------
__global__ __launch_bounds__(256, 3) void qkv_kernel(const float* __restrict__ x,
                                                     const short* __restrict__ wbf,
                                                     short* __restrict__ qb,
                                                     short* __restrict__ kb,
                                                     short* __restrict__ vb) {
  __shared__ short wt[2][12288];  // [64][192] bf16 per buffer (24KB), swizzled image
  char* wtb = (char*)wt;
  const int b = blockIdx.x, tid = threadIdx.x;
  const int wave = tid >> 6, lane = tid & 63;
  const int lr = lane & 15, g = lane >> 4, g8 = g * 8, r4 = g * 4;
  const int rowbase = wave * 32;
  const int xorkey = (lr & 7) << 4;
  const int wl = wave * 1024 + lane * 16;   // per-lane src byte offset within 4KB slab
  const int wu = wave * 1024;               // wave-uniform LDS byte offset

  // x -> fragments: rows rowbase+tf*16+lr, kdim g*8..
  short8 xa[2][6];
  {
    const float* xr = x + (size_t)b * 24576 + (size_t)(rowbase + lr) * 192;
#pragma unroll
    for (int tf = 0; tf < 2; ++tf)
#pragma unroll
      for (int ks = 0; ks < 6; ++ks) {
        const float* p = xr + tf * 16 * 192 + ks * 32 + g8;
        float4 f0 = *(const float4*)p;
        float4 f1 = *(const float4*)(p + 4);
        short8 v8;
        v8[0] = f2bf(f0.x); v8[1] = f2bf(f0.y); v8[2] = f2bf(f0.z); v8[3] = f2bf(f0.w);
        v8[4] = f2bf(f1.x); v8[5] = f2bf(f1.y); v8[6] = f2bf(f1.z); v8[7] = f2bf(f1.w);
        xa[tf][ks] = v8;
      }
  }
  // stage chunk 0 (24KB = 6 GLOADs/thread)
  {
    const char* wsrc = (const char*)wbf;
#pragma unroll
    for (int i = 0; i < 6; ++i)
      GLOAD16(wsrc + i * 4096 + wl, wtb + i * 4096 + wu);
  }
  __syncthreads();

  for (int ch = 0; ch < 9; ++ch) {
    if (ch < 8) {
      const char* wsrc = (const char*)wbf + (ch + 1) * 24576;
      char* wdst = wtb + ((ch + 1) & 1) * 24576;
#pragma unroll
      for (int i = 0; i < 6; ++i)
        GLOAD16(wsrc + i * 4096 + wl, wdst + i * 4096 + wu);
    }
    const char* wb = wtb + (ch & 1) * 24576;
    f32x4 acc[4][2];
#pragma unroll
    for (int i = 0; i < 4; ++i)
#pragma unroll
      for (int j = 0; j < 2; ++j) acc[i][j] = f32x4{0.f, 0.f, 0.f, 0.f};
    const bool isv = (ch >= 6);
    __builtin_amdgcn_s_setprio(1);
#pragma unroll
    for (int ks = 0; ks < 6; ++ks) {
      int cx = (ks * 64 + g * 16) ^ xorkey;
      short8 w[4];
#pragma unroll
      for (int c = 0; c < 4; ++c)
        w[c] = *(const short8*)(wb + (c * 16 + lr) * 384 + cx);
      if (!isv) {
        // swapped: D[wcol][tok]; acc[cf][tf]
#pragma unroll
        for (int cf = 0; cf < 4; ++cf) {
          acc[cf][0] = mfma16(w[cf], xa[0][ks], acc[cf][0]);
          acc[cf][1] = mfma16(w[cf], xa[1][ks], acc[cf][1]);
        }
      } else {
        // non-swapped: D[tok][wcol]; acc[cf][tf] holds (tok-frag tf, wcol-frag cf)
#pragma unroll
        for (int cf = 0; cf < 4; ++cf) {
          acc[cf][0] = mfma16(xa[0][ks], w[cf], acc[cf][0]);
          acc[cf][1] = mfma16(xa[1][ks], w[cf], acc[cf][1]);
        }
      }
    }
    __builtin_amdgcn_s_setprio(0);
    if (!isv) {
      const bool isq = (ch < 3);
      short* dst = isq ? qb : kb;
      const float sc = isq ? QSC : 1.0f;
      const int hbase = isq ? ch * 2 : (ch - 3) * 2;
#pragma unroll
      for (int cf = 0; cf < 4; ++cf) {
        int h = hbase + (cf >> 1);
        size_t base = ((size_t)b * 6 + h) * 4096;
        int dcol = (cf & 1) * 16 + r4;
#pragma unroll
        for (int tf = 0; tf < 2; ++tf) {
          int tok = rowbase + tf * 16 + lr;
          int idx = isq ? dcol : (dcol ^ (((tok >> 1) & 3) << 3));
          short4e s4;
          s4[0] = f2bf(acc[cf][tf][0] * sc);
          s4[1] = f2bf(acc[cf][tf][1] * sc);
          s4[2] = f2bf(acc[cf][tf][2] * sc);
          s4[3] = f2bf(acc[cf][tf][3] * sc);
          *(short4e*)&dst[base + (size_t)tok * 32 + idx] = s4;
        }
      }
    } else {
      const int hbase = (ch - 6) * 2;
#pragma unroll
      for (int cf = 0; cf < 4; ++cf) {
        int h = hbase + (cf >> 1);
        size_t base = ((size_t)b * 6 + h) * 4096;
        int d = (cf & 1) * 16 + lr;
#pragma unroll
        for (int tf = 0; tf < 2; ++tf) {
          int rowpos = rowbase + tf * 16 + r4;
          short4e s4;
          s4[0] = f2bf(acc[cf][tf][0]);
          s4[1] = f2bf(acc[cf][tf][1]);
          s4[2] = f2bf(acc[cf][tf][2]);
          s4[3] = f2bf(acc[cf][tf][3]);
          *(short4e*)&vb[base + (size_t)d * 128 + (rowpos ^ ((d & 15) << 3))] = s4;
        }
      }
    }
    if (ch < 8) __syncthreads();
  }
}

// ---------------- attn per (window,head): GLOAD k/v, q direct, 32KB LDS, 5 blk/CU ----------------
__global__ __launch_bounds__(256, 5) void attn_kernel(const short* __restrict__ qb,
                                                      const short* __restrict__ kb,
                                                      const short* __restrict__ vb,
                                                      const float* __restrict__ bmF,
                                                      char* __restrict__ outc) {
  __shared__ char sbuf[16384];   // k 8KB | v 8KB (swizzled images)
  __shared__ short p_lds[8192];  // 4 waves x 4KB P scratch
  const int bh = blockIdx.x, b = bh / 6, h = bh - b * 6;
  const short* qt = qb + (size_t)bh * 4096;
  const char* kc = (const char*)(kb + (size_t)bh * 4096);
  const char* vc = (const char*)(vb + (size_t)bh * 4096);
  const float4* bm4 = (const float4*)(bmF + ((size_t)h * 64 + (b & 63)) * 16384);
  short* outSlot = (short*)(outc + (size_t)b * 98304 + 49152);
  const int tid = threadIdx.x, wave = tid >> 6, lane = tid & 63;
  const int lr = lane & 15, g = lane >> 4, r4 = g * 4;
  const int rowbase = wave * 32;
  const int wl = wave * 1024 + lane * 16;
  const int wu = wave * 1024;

  // deep-queue stage: k,v 16KB via 4 global_load_lds per thread
  GLOAD16(kc + wl,        sbuf + wu);
  GLOAD16(kc + 4096 + wl, sbuf + 4096 + wu);
  GLOAD16(vc + wl,        sbuf + 8192 + wu);
  GLOAD16(vc + 4096 + wl, sbuf + 12288 + wu);
  // q: wave-private rows, direct global->reg (coalesced)
  short8 qaH[2];
  qaH[0] = *(const short8*)&qt[(rowbase + lr) * 32 + g * 8];
  qaH[1] = *(const short8*)&qt[(rowbase + 16 + lr) * 32 + g * 8];
  __syncthreads();

  const char* ksb = sbuf;
  const char* vs = sbuf + 8192;
  char* pw = (char*)p_lds + wave * 4096;
  const int kkey = ((lr >> 1) & 3) << 4;  // k-row swizzle key

#pragma unroll
  for (int rf = 0; rf < 2; ++rf) {
    float4 bmv[8];
#pragma unroll
    for (int i = 0; i < 8; ++i) bmv[i] = bm4[(rf * 8 + i) * 256 + tid];
    short8 qa = qaH[rf];
    f32x4 s[8];
    __builtin_amdgcn_s_setprio(1);
#pragma unroll
    for (int cf = 0; cf < 8; ++cf) {
      int krow = cf * 16 + lr;
      short8 kf = *(const short8*)(ksb + krow * 64 + ((g * 16) ^ kkey));
      f32x4 z = {0.f, 0.f, 0.f, 0.f};
      s[cf] = mfma16(qa, kf, z);
    }
    __builtin_amdgcn_s_setprio(0);
    float inv_[4];
#pragma unroll
    for (int rg = 0; rg < 4; ++rg) {
      float4 bb0 = bmv[rg * 2];
      float4 bb1 = bmv[rg * 2 + 1];
      float p0 = exp2f(s[0][rg] + bb0.x);
      float p1 = exp2f(s[1][rg] + bb0.y);
      float p2 = exp2f(s[2][rg] + bb0.z);
      float p3 = exp2f(s[3][rg] + bb0.w);
      float p4 = exp2f(s[4][rg] + bb1.x);
      float p5 = exp2f(s[5][rg] + bb1.y);
      float p6 = exp2f(s[6][rg] + bb1.z);
      float p7 = exp2f(s[7][rg] + bb1.w);
      float sum = ((p0 + p1) + (p2 + p3)) + ((p4 + p5) + (p6 + p7));
#pragma unroll
      for (int o = 1; o < 16; o <<= 1) sum += __shfl_xor(sum, o);
      inv_[rg] = 1.0f / sum;
      int rr = r4 + rg;
      int base = rr * 256 + (lr << 1);
      int swz = rr << 4;
      *(short*)(pw + ((base + 0 * 32) ^ swz)) = f2bf(p0);
      *(short*)(pw + ((base + 1 * 32) ^ swz)) = f2bf(p1);
      *(short*)(pw + ((base + 2 * 32) ^ swz)) = f2bf(p2);
      *(short*)(pw + ((base + 3 * 32) ^ swz)) = f2bf(p3);
      *(short*)(pw + ((base + 4 * 32) ^ swz)) = f2bf(p4);
      *(short*)(pw + ((base + 5 * 32) ^ swz)) = f2bf(p5);
      *(short*)(pw + ((base + 6 * 32) ^ swz)) = f2bf(p6);
      *(short*)(pw + ((base + 7 * 32) ^ swz)) = f2bf(p7);
    }
    f32x4 o0 = {0.f, 0.f, 0.f, 0.f}, o1 = {0.f, 0.f, 0.f, 0.f};
#pragma unroll
    for (int kst = 0; kst < 4; ++kst) {
      short8 pa = *(const short8*)(pw + ((lr * 256 + kst * 64 + g * 16) ^ (lr << 4)));
      short8 vb0 = *(const short8*)(vs + ((lr * 256 + kst * 64 + g * 16) ^ ((lr & 15) << 4)));
      short8 vb1 = *(const short8*)(vs + (((16 + lr) * 256 + kst * 64 + g * 16) ^ (((16 + lr) & 15) << 4)));
      __builtin_amdgcn_s_setprio(1);
      o0 = mfma16(pa, vb0, o0);
      o1 = mfma16(pa, vb1, o1);
      __builtin_amdgcn_s_setprio(0);
    }
#pragma unroll
    for (int rg = 0; rg < 4; ++rg) {
      int tok = rowbase + rf * 16 + r4 + rg;
      float iv = inv_[rg];
      outSlot[(size_t)tok * 192 + h * 32 + lr] = f2bf(o0[rg] * iv);
      outSlot[(size_t)tok * 192 + h * 32 + 16 + lr] = f2bf(o1[rg] * iv);
    }
  }
}

// ---------------- proj: ain[128][192] (bf16 in own d_out slot) @ proj_w^T + b ----------------
__global__ __launch_bounds__(256, 2) void proj_kernel(const short* __restrict__ pwbf,
                                                      const float* __restrict__ pb,
                                                      float* __restrict__ out) {
  __shared__ short at[24576];
  __shared__ short wt[2][6144];
  const int b = blockIdx.x, tid = threadIdx.x;
  const int wave = tid >> 6, lane = tid & 63;
  const int lr = lane & 15, g = lane >> 4;
  const int g16 = g * 16, r4 = g * 4;
  const int rowbase = wave * 32;
  const int xorkey = (lr & 7) << 4;
  char* atb = (char*)at;
  char* wtb = (char*)wt;

  int wsoff[3], wdoff[3];
#pragma unroll
  for (int i = 0; i < 3; ++i) {
    int idx8 = i * 256 + tid;
    int r = idx8 / 24, c = idx8 - r * 24;
    wsoff[i] = idx8 * 8;
    wdoff[i] = r * 384 + ((c * 16) ^ ((r & 7) << 4));
  }
  short8 wreg[3];
#pragma unroll
  for (int i = 0; i < 3; ++i) wreg[i] = *(const short8*)(pwbf + wsoff[i]);

  const short8* ar = (const short8*)((const char*)out + (size_t)b * 98304 + 49152);
#pragma unroll
  for (int i = 0; i < 12; ++i) {
    int idx8 = i * 256 + tid;
    int r = idx8 / 24, c = idx8 - r * 24;
    short8 v = ar[idx8];
    *(short8*)(atb + r * 384 + ((c * 16) ^ ((r & 7) << 4))) = v;
  }
#pragma unroll
  for (int i = 0; i < 3; ++i) *(short8*)(wtb + wdoff[i]) = wreg[i];
  __syncthreads();

  const int rA0 = (rowbase + lr) * 384, rA1 = rA0 + 16 * 384;
  const int wB0 = lr * 384, wB1 = wB0 + 16 * 384;

  for (int ch = 0; ch < 6; ++ch) {
    if (ch < 5) {
#pragma unroll
      for (int i = 0; i < 3; ++i)
        wreg[i] = *(const short8*)(pwbf + (ch + 1) * 6144 + wsoff[i]);
    }
    const char* wbuf = wtb + (ch & 1) * 12288;
    f32x4 acc[2][2];
    acc[0][0] = acc[0][1] = acc[1][0] = acc[1][1] = f32x4{0.f, 0.f, 0.f, 0.f};
#pragma unroll
    for (int ks = 0; ks < 6; ++ks) {
      int cx = (ks * 64 + g16) ^ xorkey;
      short8 xa0 = *(const short8*)(atb + rA0 + cx);
      short8 xa1 = *(const short8*)(atb + rA1 + cx);
      short8 wf0 = *(const short8*)(wbuf + wB0 + cx);
      short8 wf1 = *(const short8*)(wbuf + wB1 + cx);
      acc[0][0] = mfma16(xa0, wf0, acc[0][0]);
      acc[0][1] = mfma16(xa0, wf1, acc[0][1]);
      acc[1][0] = mfma16(xa1, wf0, acc[1][0]);
      acc[1][1] = mfma16(xa1, wf1, acc[1][1]);
    }
#pragma unroll
    for (int cf = 0; cf < 2; ++cf) {
      int j = ch * 32 + cf * 16 + lr;
      float bj = pb[j];
#pragma unroll
      for (int rf = 0; rf < 2; ++rf)
#pragma unroll
        for (int rg = 0; rg < 4; ++rg) {
          int tok = rowbase + rf * 16 + r4 + rg;
          out[((size_t)b * 128 + tok) * 192 + j] = acc[rf][cf][rg] + bj;
        }
    }
    if (ch < 5) {
#pragma unroll
      for (int i = 0; i < 3; ++i)
        *(short8*)(wtb + ((ch + 1) & 1) * 12288 + wdoff[i]) = wreg[i];
      __syncthreads();
    }
  }
}

extern "C" void kernel_launch(void* const* d_in, const int* in_sizes, int n_in,
                              void* d_out, int out_size, void* d_ws, size_t ws_size,
                              hipStream_t stream) {
  const float* x      = (const float*)d_in[0];
  const float* mask   = (const float*)d_in[1];
  const float* qkv_w  = (const float*)d_in[2];
  const float* proj_w = (const float*)d_in[3];
  const float* proj_b = (const float*)d_in[4];
  const float* table  = (const float*)d_in[5];
  const int*   rel    = (const int*)d_in[6];
  char* ws = (char*)d_ws;
  size_t o = 0;
  float* bmF  = (float*)(ws + o); o += 25165824;   // 384 * 16384 * 4
  short* wbf  = (short*)(ws + o); o += 221184;
  short* pwbf = (short*)(ws + o); o += 73728;
  short* qbp  = (short*)(ws + o); o += 50331648;
  short* kbp  = (short*)(ws + o); o += 50331648;
  short* vbp  = (short*)(ws + o); o += 50331648;
  float* out = (float*)d_out;

  prep_w<<<144, 256, 0, stream>>>(qkv_w, proj_w, wbf, pwbf);
  prep_bm<<<384, 256, 0, stream>>>(rel, table, mask, bmF);
  qkv_kernel<<<1024, 256, 0, stream>>>(x, wbf, qbp, kbp, vbp);
  attn_kernel<<<6144, 256, 0, stream>>>(qbp, kbp, vbp, bmF, (char*)d_out);
  proj_kernel<<<1024, 256, 0, stream>>>(pwbf, proj_b, (float*)d_out);
}

// Round 14
// 184.285 us; speedup vs baseline: 1.7035x; 1.3621x over previous
//
#include <hip/hip_runtime.h>
#include <hip/hip_bf16.h>

// WindowAttention v14: r13 with the vmcnt count FIXED (4 stores/chunk, not 8).
// Counted-vmcnt barriers in qkv: drain the 3 GLOADs, let this chunk's 4 stores
// overlap the next chunk's MFMAs. Rest identical to r10 (184us proven).
// N=128 tokens, B_=1024 windows, C=192, H=6, hd=32.
// ws: bmF f32 [6*64][16384] ((bias+mask)*LOG2E, r6 frag order) |
//     wbf bf16[576][192] GLOBAL-SWIZZLED (short col ^ (row&7)<<3) | pwbf linear |
//     q bf16 [b][h][128][32] linear, pre-scaled SCALE*LOG2E |
//     k swz (short col ^ ((tok>>1)&3)<<3) | v^T swz (short col ^ (d&15)<<3)
// attn bf16 out in d_out slot: d_out + b*98304 + 49152 (block-private).

typedef float f32x4 __attribute__((ext_vector_type(4)));
typedef short short8 __attribute__((ext_vector_type(8)));
typedef short short4e __attribute__((ext_vector_type(4)));

#define SCALE 0.17677669529663687f
#define LOG2E 1.4426950408889634f
#define QSC (SCALE * LOG2E)

#define GLOAD16(src, dst)                                                      \
  __builtin_amdgcn_global_load_lds(                                            \
      (const __attribute__((address_space(1))) unsigned int*)(const void*)(src),\
      (__attribute__((address_space(3))) unsigned int*)(void*)(dst), 16, 0, 0)

static __device__ __forceinline__ short f2bf(float f) {
  __hip_bfloat16 h = __float2bfloat16(f);
  return __builtin_bit_cast(short, h);
}
static __device__ __forceinline__ f32x4 mfma16(short8 a, short8 b, f32x4 c) {
  return __builtin_amdgcn_mfma_f32_16x16x32_bf16(a, b, c, 0, 0, 0);
}

// ---------------- prep: qkv_w -> bf16 swizzled, proj_w -> bf16 linear ----------------
__global__ __launch_bounds__(256) void prep_w(const float* __restrict__ qkvw,
                                              const float* __restrict__ projw,
                                              short* __restrict__ wbf,
                                              short* __restrict__ pwbf) {
  int t = blockIdx.x * 256 + threadIdx.x;  // float4 index 0..36863
  const int NQ = 27648;                    // 576*192/4
  float4 f; short* dst;
  if (t < NQ) {
    f = ((const float4*)qkvw)[t];
    int row = (t * 4) / 192, c4 = (t * 4) % 192;
    dst = wbf + row * 192 + (c4 ^ ((row & 7) << 3));  // row-local: key<=56<192 shorts
  } else {
    f = ((const float4*)projw)[t - NQ];
    dst = pwbf + (t - NQ) * 4;
  }
  short4e o; o[0] = f2bf(f.x); o[1] = f2bf(f.y); o[2] = f2bf(f.z); o[3] = f2bf(f.w);
  *(short4e*)dst = o;
}

// ---------------- prep_bm: (bias+mask)*LOG2E tiles, r6 fragment layout ----------------
__global__ __launch_bounds__(256) void prep_bm(const int* __restrict__ rel,
                                               const float* __restrict__ table,
                                               const float* __restrict__ mask,
                                               float* __restrict__ bmF) {
  int blk = blockIdx.x;            // 384 blocks: h*64 + w
  int h = blk >> 6, w = blk & 63;
  int tid = threadIdx.x, lane = tid & 63, wave = tid >> 6;
  int lr = lane & 15, r4 = (lane >> 4) * 4;
  const float* mk = mask + (size_t)w * 16384;
  float* dst = bmF + (size_t)blk * 16384;
#pragma unroll
  for (int L = 0; L < 16; ++L) {
    int rf = L >> 3, rg = (L >> 1) & 3, cp = L & 1;
    int row = wave * 32 + rf * 16 + r4 + rg;
    float4 v;
#pragma unroll
    for (int e = 0; e < 4; ++e) {
      int col = (cp * 4 + e) * 16 + lr;
      float bias = table[rel[row * 128 + col] * 6 + h];
      ((float*)&v)[e] = (bias + mk[row * 128 + col]) * LOG2E;
    }
    ((float4*)dst)[L * 256 + tid] = v;
  }
}

// ---------------- qkv: x in regs, W via GLOAD; counted-vmcnt(4) barriers ----------------
__global__ __launch_bounds__(256, 4) void qkv_kernel(const float* __restrict__ x,
                                                     const short* __restrict__ wbf,
                                                     short* __restrict__ qb,
                                                     short* __restrict__ kb,
                                                     short* __restrict__ vb) {
  __shared__ short wt[2][6144];  // [32][192] bf16 dbuf, image already swizzled
  char* wtb = (char*)wt;
  const int b = blockIdx.x, tid = threadIdx.x;
  const int wave = tid >> 6, lane = tid & 63;
  const int lr = lane & 15, g = lane >> 4, g8 = g * 8, r4 = g * 4;
  const int rowbase = wave * 32;
  const int xorkey = (lr & 7) << 4;
  const int wl = wave * 1024 + lane * 16;   // per-lane src byte offset
  const int wu = wave * 1024;               // wave-uniform LDS byte offset

  // x -> fragments: rows rowbase+tf*16+lr, kdim g*8..
  short8 xa[2][6];
  {
    const float* xr = x + (size_t)b * 24576 + (size_t)(rowbase + lr) * 192;
#pragma unroll
    for (int tf = 0; tf < 2; ++tf)
#pragma unroll
      for (int ks = 0; ks < 6; ++ks) {
        const float* p = xr + tf * 16 * 192 + ks * 32 + g8;
        float4 f0 = *(const float4*)p;
        float4 f1 = *(const float4*)(p + 4);
        short8 v8;
        v8[0] = f2bf(f0.x); v8[1] = f2bf(f0.y); v8[2] = f2bf(f0.z); v8[3] = f2bf(f0.w);
        v8[4] = f2bf(f1.x); v8[5] = f2bf(f1.y); v8[6] = f2bf(f1.z); v8[7] = f2bf(f1.w);
        xa[tf][ks] = v8;
      }
  }
  // stage chunk 0
  {
    const char* wsrc = (const char*)wbf;
#pragma unroll
    for (int i = 0; i < 3; ++i)
      GLOAD16(wsrc + i * 4096 + wl, wtb + i * 4096 + wu);
  }
  __syncthreads();

  // ---- chunks 0..11: q,k — swapped MFMA, D[wcol][tok] ----
  for (int ch = 0; ch < 12; ++ch) {
    {
      const char* wsrc = (const char*)wbf + (ch + 1) * 12288;
      char* wdst = wtb + ((ch + 1) & 1) * 12288;
#pragma unroll
      for (int i = 0; i < 3; ++i)
        GLOAD16(wsrc + i * 4096 + wl, wdst + i * 4096 + wu);
    }
    __builtin_amdgcn_sched_barrier(0);  // pin: GLOADs issue before compute/stores
    const char* wb = wtb + (ch & 1) * 12288;
    f32x4 acc[2][2];
    acc[0][0] = acc[0][1] = acc[1][0] = acc[1][1] = f32x4{0.f, 0.f, 0.f, 0.f};
    __builtin_amdgcn_s_setprio(1);
#pragma unroll
    for (int ks = 0; ks < 6; ++ks) {
      int cx = (ks * 64 + g * 16) ^ xorkey;
      short8 w0 = *(const short8*)(wb + lr * 384 + cx);
      short8 w1 = *(const short8*)(wb + (16 + lr) * 384 + cx);
      acc[0][0] = mfma16(w0, xa[0][ks], acc[0][0]);
      acc[0][1] = mfma16(w0, xa[1][ks], acc[0][1]);
      acc[1][0] = mfma16(w1, xa[0][ks], acc[1][0]);
      acc[1][1] = mfma16(w1, xa[1][ks], acc[1][1]);
    }
    __builtin_amdgcn_s_setprio(0);
    bool isq = (ch < 6);
    short* dst = isq ? qb : kb;
    int h = isq ? ch : ch - 6;
    float sc = isq ? QSC : 1.0f;
    size_t base = ((size_t)b * 6 + h) * 4096;
#pragma unroll
    for (int cf = 0; cf < 2; ++cf)
#pragma unroll
      for (int tf = 0; tf < 2; ++tf) {
        int tok = rowbase + tf * 16 + lr;
        int col = cf * 16 + r4;
        int idx = isq ? col : (col ^ (((tok >> 1) & 3) << 3));
        short4e s4;
        s4[0] = f2bf(acc[cf][tf][0] * sc);
        s4[1] = f2bf(acc[cf][tf][1] * sc);
        s4[2] = f2bf(acc[cf][tf][2] * sc);
        s4[3] = f2bf(acc[cf][tf][3] * sc);
        *(short4e*)&dst[base + (size_t)tok * 32 + idx] = s4;
      }
    // counted barrier: 4 stores (newest) may stay in flight; 3 GLOADs drained.
    __builtin_amdgcn_sched_barrier(0);
    asm volatile("s_waitcnt vmcnt(4)" ::: "memory");
    __builtin_amdgcn_s_barrier();
    __builtin_amdgcn_sched_barrier(0);
  }
  // ---- chunks 12..17: v — non-swapped, D[tok][wcol], swizzled v^T stores ----
  for (int ch = 12; ch < 18; ++ch) {
    if (ch < 17) {
      const char* wsrc = (const char*)wbf + (ch + 1) * 12288;
      char* wdst = wtb + ((ch + 1) & 1) * 12288;
#pragma unroll
      for (int i = 0; i < 3; ++i)
        GLOAD16(wsrc + i * 4096 + wl, wdst + i * 4096 + wu);
    }
    __builtin_amdgcn_sched_barrier(0);
    const char* wb = wtb + (ch & 1) * 12288;
    f32x4 acc[2][2];  // [tf][cf]
    acc[0][0] = acc[0][1] = acc[1][0] = acc[1][1] = f32x4{0.f, 0.f, 0.f, 0.f};
    __builtin_amdgcn_s_setprio(1);
#pragma unroll
    for (int ks = 0; ks < 6; ++ks) {
      int cx = (ks * 64 + g * 16) ^ xorkey;
      short8 w0 = *(const short8*)(wb + lr * 384 + cx);
      short8 w1 = *(const short8*)(wb + (16 + lr) * 384 + cx);
      acc[0][0] = mfma16(xa[0][ks], w0, acc[0][0]);
      acc[0][1] = mfma16(xa[0][ks], w1, acc[0][1]);
      acc[1][0] = mfma16(xa[1][ks], w0, acc[1][0]);
      acc[1][1] = mfma16(xa[1][ks], w1, acc[1][1]);
    }
    __builtin_amdgcn_s_setprio(0);
    int h = ch - 12;
    size_t base = ((size_t)b * 6 + h) * 4096;
#pragma unroll
    for (int tf = 0; tf < 2; ++tf)
#pragma unroll
      for (int cf = 0; cf < 2; ++cf) {
        int d = cf * 16 + lr;
        int rowpos = rowbase + tf * 16 + r4;
        short4e s4;
        s4[0] = f2bf(acc[tf][cf][0]);
        s4[1] = f2bf(acc[tf][cf][1]);
        s4[2] = f2bf(acc[tf][cf][2]);
        s4[3] = f2bf(acc[tf][cf][3]);
        *(short4e*)&vb[base + (size_t)d * 128 + (rowpos ^ ((d & 15) << 3))] = s4;
      }
    if (ch < 17) {
      __builtin_amdgcn_sched_barrier(0);
      asm volatile("s_waitcnt vmcnt(4)" ::: "memory");
      __builtin_amdgcn_s_barrier();
      __builtin_amdgcn_sched_barrier(0);
    }
  }
}

// ---------------- attn per (window,head): GLOAD k/v, q direct, 32KB LDS, 4 blk/CU ----------------
__global__ __launch_bounds__(256, 4) void attn_kernel(const short* __restrict__ qb,
                                                      const short* __restrict__ kb,
                                                      const short* __restrict__ vb,
                                                      const float* __restrict__ bmF,
                                                      char* __restrict__ outc) {
  __shared__ char sbuf[16384];   // k 8KB | v 8KB (swizzled images)
  __shared__ short p_lds[8192];  // 4 waves x 4KB P scratch
  const int bh = blockIdx.x, b = bh / 6, h = bh - b * 6;
  const short* qt = qb + (size_t)bh * 4096;
  const char* kc = (const char*)(kb + (size_t)bh * 4096);
  const char* vc = (const char*)(vb + (size_t)bh * 4096);
  const float4* bm4 = (const float4*)(bmF + ((size_t)h * 64 + (b & 63)) * 16384);
  short* outSlot = (short*)(outc + (size_t)b * 98304 + 49152);
  const int tid = threadIdx.x, wave = tid >> 6, lane = tid & 63;
  const int lr = lane & 15, g = lane >> 4, r4 = g * 4;
  const int rowbase = wave * 32;
  const int wl = wave * 1024 + lane * 16;
  const int wu = wave * 1024;

  // deep-queue stage: k,v 16KB via 4 global_load_lds per thread
  GLOAD16(kc + wl,        sbuf + wu);
  GLOAD16(kc + 4096 + wl, sbuf + 4096 + wu);
  GLOAD16(vc + wl,        sbuf + 8192 + wu);
  GLOAD16(vc + 4096 + wl, sbuf + 12288 + wu);
  // q: wave-private rows, direct global->reg (coalesced), independent of LDS
  short8 qaH[2];
  qaH[0] = *(const short8*)&qt[(rowbase + lr) * 32 + g * 8];
  qaH[1] = *(const short8*)&qt[(rowbase + 16 + lr) * 32 + g * 8];
  __syncthreads();

  const char* ksb = sbuf;
  const char* vs = sbuf + 8192;
  char* pw = (char*)p_lds + wave * 4096;
  const int kkey = ((lr >> 1) & 3) << 4;  // k-row swizzle key (krow>>1)&3 == (lr>>1)&3

#pragma unroll
  for (int rf = 0; rf < 2; ++rf) {
    // prefetch bias+mask fragments for this rf (8 x 16B)
    float4 bmv[8];
#pragma unroll
    for (int i = 0; i < 8; ++i) bmv[i] = bm4[(rf * 8 + i) * 256 + tid];
    short8 qa = qaH[rf];
    f32x4 s[8];
    __builtin_amdgcn_s_setprio(1);
#pragma unroll
    for (int cf = 0; cf < 8; ++cf) {
      int krow = cf * 16 + lr;
      short8 kf = *(const short8*)(ksb + krow * 64 + ((g * 16) ^ kkey));
      f32x4 z = {0.f, 0.f, 0.f, 0.f};
      s[cf] = mfma16(qa, kf, z);
    }
    __builtin_amdgcn_s_setprio(0);
    float inv_[4];
#pragma unroll
    for (int rg = 0; rg < 4; ++rg) {
      float4 bb0 = bmv[rg * 2];
      float4 bb1 = bmv[rg * 2 + 1];
      float p0 = exp2f(s[0][rg] + bb0.x);
      float p1 = exp2f(s[1][rg] + bb0.y);
      float p2 = exp2f(s[2][rg] + bb0.z);
      float p3 = exp2f(s[3][rg] + bb0.w);
      float p4 = exp2f(s[4][rg] + bb1.x);
      float p5 = exp2f(s[5][rg] + bb1.y);
      float p6 = exp2f(s[6][rg] + bb1.z);
      float p7 = exp2f(s[7][rg] + bb1.w);
      float sum = ((p0 + p1) + (p2 + p3)) + ((p4 + p5) + (p6 + p7));
#pragma unroll
      for (int o = 1; o < 16; o <<= 1) sum += __shfl_xor(sum, o);
      inv_[rg] = 1.0f / sum;
      int rr = r4 + rg;                 // row within this rf's 16
      int base = rr * 256 + (lr << 1);
      int swz = rr << 4;
      *(short*)(pw + ((base + 0 * 32) ^ swz)) = f2bf(p0);
      *(short*)(pw + ((base + 1 * 32) ^ swz)) = f2bf(p1);
      *(short*)(pw + ((base + 2 * 32) ^ swz)) = f2bf(p2);
      *(short*)(pw + ((base + 3 * 32) ^ swz)) = f2bf(p3);
      *(short*)(pw + ((base + 4 * 32) ^ swz)) = f2bf(p4);
      *(short*)(pw + ((base + 5 * 32) ^ swz)) = f2bf(p5);
      *(short*)(pw + ((base + 6 * 32) ^ swz)) = f2bf(p6);
      *(short*)(pw + ((base + 7 * 32) ^ swz)) = f2bf(p7);
    }
    // PV: D[qtok][d]; P (wave-private) + V from LDS, no barrier
    f32x4 o0 = {0.f, 0.f, 0.f, 0.f}, o1 = {0.f, 0.f, 0.f, 0.f};
#pragma unroll
    for (int kst = 0; kst < 4; ++kst) {
      short8 pa = *(const short8*)(pw + ((lr * 256 + kst * 64 + g * 16) ^ (lr << 4)));
      short8 vb0 = *(const short8*)(vs + ((lr * 256 + kst * 64 + g * 16) ^ ((lr & 15) << 4)));
      short8 vb1 = *(const short8*)(vs + (((16 + lr) * 256 + kst * 64 + g * 16) ^ (((16 + lr) & 15) << 4)));
      __builtin_amdgcn_s_setprio(1);
      o0 = mfma16(pa, vb0, o0);
      o1 = mfma16(pa, vb1, o1);
      __builtin_amdgcn_s_setprio(0);
    }
    // epilogue (round-6 proven scalar form)
#pragma unroll
    for (int rg = 0; rg < 4; ++rg) {
      int tok = rowbase + rf * 16 + r4 + rg;
      float iv = inv_[rg];
      outSlot[(size_t)tok * 192 + h * 32 + lr] = f2bf(o0[rg] * iv);
      outSlot[(size_t)tok * 192 + h * 32 + 16 + lr] = f2bf(o1[rg] * iv);
    }
  }
}

// ---------------- proj: ain[128][192] (bf16 in own d_out slot) @ proj_w^T + b ----------------
__global__ __launch_bounds__(256, 2) void proj_kernel(const short* __restrict__ pwbf,
                                                      const float* __restrict__ pb,
                                                      float* __restrict__ out) {
  __shared__ short at[24576];
  __shared__ short wt[2][6144];
  const int b = blockIdx.x, tid = threadIdx.x;
  const int wave = tid >> 6, lane = tid & 63;
  const int lr = lane & 15, g = lane >> 4;
  const int g16 = g * 16, r4 = g * 4;
  const int rowbase = wave * 32;
  const int xorkey = (lr & 7) << 4;
  char* atb = (char*)at;
  char* wtb = (char*)wt;

  int wsoff[3], wdoff[3];
#pragma unroll
  for (int i = 0; i < 3; ++i) {
    int idx8 = i * 256 + tid;
    int r = idx8 / 24, c = idx8 - r * 24;
    wsoff[i] = idx8 * 8;
    wdoff[i] = r * 384 + ((c * 16) ^ ((r & 7) << 4));
  }
  short8 wreg[3];
#pragma unroll
  for (int i = 0; i < 3; ++i) wreg[i] = *(const short8*)(pwbf + wsoff[i]);

  const short8* ar = (const short8*)((const char*)out + (size_t)b * 98304 + 49152);
#pragma unroll
  for (int i = 0; i < 12; ++i) {
    int idx8 = i * 256 + tid;
    int r = idx8 / 24, c = idx8 - r * 24;
    short8 v = ar[idx8];
    *(short8*)(atb + r * 384 + ((c * 16) ^ ((r & 7) << 4))) = v;
  }
#pragma unroll
  for (int i = 0; i < 3; ++i) *(short8*)(wtb + wdoff[i]) = wreg[i];
  __syncthreads();

  const int rA0 = (rowbase + lr) * 384, rA1 = rA0 + 16 * 384;
  const int wB0 = lr * 384, wB1 = wB0 + 16 * 384;

  for (int ch = 0; ch < 6; ++ch) {
    if (ch < 5) {
#pragma unroll
      for (int i = 0; i < 3; ++i)
        wreg[i] = *(const short8*)(pwbf + (ch + 1) * 6144 + wsoff[i]);
    }
    const char* wbuf = wtb + (ch & 1) * 12288;
    f32x4 acc[2][2];
    acc[0][0] = acc[0][1] = acc[1][0] = acc[1][1] = f32x4{0.f, 0.f, 0.f, 0.f};
#pragma unroll
    for (int ks = 0; ks < 6; ++ks) {
      int cx = (ks * 64 + g16) ^ xorkey;
      short8 xa0 = *(const short8*)(atb + rA0 + cx);
      short8 xa1 = *(const short8*)(atb + rA1 + cx);
      short8 wf0 = *(const short8*)(wbuf + wB0 + cx);
      short8 wf1 = *(const short8*)(wbuf + wB1 + cx);
      acc[0][0] = mfma16(xa0, wf0, acc[0][0]);
      acc[0][1] = mfma16(xa0, wf1, acc[0][1]);
      acc[1][0] = mfma16(xa1, wf0, acc[1][0]);
      acc[1][1] = mfma16(xa1, wf1, acc[1][1]);
    }
#pragma unroll
    for (int cf = 0; cf < 2; ++cf) {
      int j = ch * 32 + cf * 16 + lr;
      float bj = pb[j];
#pragma unroll
      for (int rf = 0; rf < 2; ++rf)
#pragma unroll
        for (int rg = 0; rg < 4; ++rg) {
          int tok = rowbase + rf * 16 + r4 + rg;
          out[((size_t)b * 128 + tok) * 192 + j] = acc[rf][cf][rg] + bj;
        }
    }
    if (ch < 5) {
#pragma unroll
      for (int i = 0; i < 3; ++i)
        *(short8*)(wtb + ((ch + 1) & 1) * 12288 + wdoff[i]) = wreg[i];
      __syncthreads();
    }
  }
}

extern "C" void kernel_launch(void* const* d_in, const int* in_sizes, int n_in,
                              void* d_out, int out_size, void* d_ws, size_t ws_size,
                              hipStream_t stream) {
  const float* x      = (const float*)d_in[0];
  const float* mask   = (const float*)d_in[1];
  const float* qkv_w  = (const float*)d_in[2];
  const float* proj_w = (const float*)d_in[3];
  const float* proj_b = (const float*)d_in[4];
  const float* table  = (const float*)d_in[5];
  const int*   rel    = (const int*)d_in[6];
  char* ws = (char*)d_ws;
  size_t o = 0;
  float* bmF  = (float*)(ws + o); o += 25165824;   // 384 * 16384 * 4
  short* wbf  = (short*)(ws + o); o += 221184;
  short* pwbf = (short*)(ws + o); o += 73728;
  short* qbp  = (short*)(ws + o); o += 50331648;
  short* kbp  = (short*)(ws + o); o += 50331648;
  short* vbp  = (short*)(ws + o); o += 50331648;
  float* out = (float*)d_out;

  prep_w<<<144, 256, 0, stream>>>(qkv_w, proj_w, wbf, pwbf);
  prep_bm<<<384, 256, 0, stream>>>(rel, table, mask, bmF);
  qkv_kernel<<<1024, 256, 0, stream>>>(x, wbf, qbp, kbp, vbp);
  attn_kernel<<<6144, 256, 0, stream>>>(qbp, kbp, vbp, bmF, (char*)d_out);
  proj_kernel<<<1024, 256, 0, stream>>>(pwbf, proj_b, (float*)d_out);
}

// Round 15
// 182.409 us; speedup vs baseline: 1.7210x; 1.0103x over previous
//
#include <hip/hip_runtime.h>
#include <hip/hip_bf16.h>

// WindowAttention v15: r14 pipeline; qkv upgraded to a 3-deep GLOAD pipeline
// (triple-buffered W, G(ch+2) issued during chunk ch, exact vmcnt(11) waits,
// lb(256,3) for VGPR headroom). attn/proj/prep identical to r14 (184us proven).
// N=128 tokens, B_=1024 windows, C=192, H=6, hd=32.
// ws: bmF f32 [6*64][16384] ((bias+mask)*LOG2E, r6 frag order) |
//     wbf bf16[576][192] GLOBAL-SWIZZLED (short col ^ (row&7)<<3) | pwbf linear |
//     q bf16 [b][h][128][32] linear, pre-scaled SCALE*LOG2E |
//     k swz (short col ^ ((tok>>1)&3)<<3) | v^T swz (short col ^ (d&15)<<3)
// attn bf16 out in d_out slot: d_out + b*98304 + 49152 (block-private).

typedef float f32x4 __attribute__((ext_vector_type(4)));
typedef short short8 __attribute__((ext_vector_type(8)));
typedef short short4e __attribute__((ext_vector_type(4)));

#define SCALE 0.17677669529663687f
#define LOG2E 1.4426950408889634f
#define QSC (SCALE * LOG2E)

#define GLOAD16(src, dst)                                                      \
  __builtin_amdgcn_global_load_lds(                                            \
      (const __attribute__((address_space(1))) unsigned int*)(const void*)(src),\
      (__attribute__((address_space(3))) unsigned int*)(void*)(dst), 16, 0, 0)

static __device__ __forceinline__ short f2bf(float f) {
  __hip_bfloat16 h = __float2bfloat16(f);
  return __builtin_bit_cast(short, h);
}
static __device__ __forceinline__ f32x4 mfma16(short8 a, short8 b, f32x4 c) {
  return __builtin_amdgcn_mfma_f32_16x16x32_bf16(a, b, c, 0, 0, 0);
}

// ---------------- prep: qkv_w -> bf16 swizzled, proj_w -> bf16 linear ----------------
__global__ __launch_bounds__(256) void prep_w(const float* __restrict__ qkvw,
                                              const float* __restrict__ projw,
                                              short* __restrict__ wbf,
                                              short* __restrict__ pwbf) {
  int t = blockIdx.x * 256 + threadIdx.x;  // float4 index 0..36863
  const int NQ = 27648;                    // 576*192/4
  float4 f; short* dst;
  if (t < NQ) {
    f = ((const float4*)qkvw)[t];
    int row = (t * 4) / 192, c4 = (t * 4) % 192;
    dst = wbf + row * 192 + (c4 ^ ((row & 7) << 3));  // row-local: key<=56<192 shorts
  } else {
    f = ((const float4*)projw)[t - NQ];
    dst = pwbf + (t - NQ) * 4;
  }
  short4e o; o[0] = f2bf(f.x); o[1] = f2bf(f.y); o[2] = f2bf(f.z); o[3] = f2bf(f.w);
  *(short4e*)dst = o;
}

// ---------------- prep_bm: (bias+mask)*LOG2E tiles, r6 fragment layout ----------------
__global__ __launch_bounds__(256) void prep_bm(const int* __restrict__ rel,
                                               const float* __restrict__ table,
                                               const float* __restrict__ mask,
                                               float* __restrict__ bmF) {
  int blk = blockIdx.x;            // 384 blocks: h*64 + w
  int h = blk >> 6, w = blk & 63;
  int tid = threadIdx.x, lane = tid & 63, wave = tid >> 6;
  int lr = lane & 15, r4 = (lane >> 4) * 4;
  const float* mk = mask + (size_t)w * 16384;
  float* dst = bmF + (size_t)blk * 16384;
#pragma unroll
  for (int L = 0; L < 16; ++L) {
    int rf = L >> 3, rg = (L >> 1) & 3, cp = L & 1;
    int row = wave * 32 + rf * 16 + r4 + rg;
    float4 v;
#pragma unroll
    for (int e = 0; e < 4; ++e) {
      int col = (cp * 4 + e) * 16 + lr;
      float bias = table[rel[row * 128 + col] * 6 + h];
      ((float*)&v)[e] = (bias + mk[row * 128 + col]) * LOG2E;
    }
    ((float4*)dst)[L * 256 + tid] = v;
  }
}

// ---------------- qkv: x in regs, W via 3-deep GLOAD pipeline ----------------
__global__ __launch_bounds__(256, 3) void qkv_kernel(const float* __restrict__ x,
                                                     const short* __restrict__ wbf,
                                                     short* __restrict__ qb,
                                                     short* __restrict__ kb,
                                                     short* __restrict__ vb) {
  __shared__ short wt[3][6144];  // [32][192] bf16 triple buffer (36KB), swizzled image
  char* wtb = (char*)wt;
  const int b = blockIdx.x, tid = threadIdx.x;
  const int wave = tid >> 6, lane = tid & 63;
  const int lr = lane & 15, g = lane >> 4, g8 = g * 8, r4 = g * 4;
  const int rowbase = wave * 32;
  const int xorkey = (lr & 7) << 4;
  const int wl = wave * 1024 + lane * 16;   // per-lane src byte offset
  const int wu = wave * 1024;               // wave-uniform LDS byte offset

  // x -> fragments: rows rowbase+tf*16+lr, kdim g*8..
  short8 xa[2][6];
  {
    const float* xr = x + (size_t)b * 24576 + (size_t)(rowbase + lr) * 192;
#pragma unroll
    for (int tf = 0; tf < 2; ++tf)
#pragma unroll
      for (int ks = 0; ks < 6; ++ks) {
        const float* p = xr + tf * 16 * 192 + ks * 32 + g8;
        float4 f0 = *(const float4*)p;
        float4 f1 = *(const float4*)(p + 4);
        short8 v8;
        v8[0] = f2bf(f0.x); v8[1] = f2bf(f0.y); v8[2] = f2bf(f0.z); v8[3] = f2bf(f0.w);
        v8[4] = f2bf(f1.x); v8[5] = f2bf(f1.y); v8[6] = f2bf(f1.z); v8[7] = f2bf(f1.w);
        xa[tf][ks] = v8;
      }
  }
  // prologue: stage chunks 0 and 1
#pragma unroll
  for (int c0 = 0; c0 < 2; ++c0) {
    const char* wsrc = (const char*)wbf + c0 * 12288;
#pragma unroll
    for (int i = 0; i < 3; ++i)
      GLOAD16(wsrc + i * 4096 + wl, wtb + c0 * 12288 + i * 4096 + wu);
  }
  __builtin_amdgcn_sched_barrier(0);
  asm volatile("s_waitcnt vmcnt(3)" ::: "memory");  // G(0) done; G(1) in flight
  __builtin_amdgcn_s_barrier();
  __builtin_amdgcn_sched_barrier(0);

#pragma unroll
  for (int ch = 0; ch < 18; ++ch) {
    if (ch + 2 < 18) {
      const char* wsrc = (const char*)wbf + (ch + 2) * 12288;
      char* wdst = wtb + ((ch + 2) % 3) * 12288;
#pragma unroll
      for (int i = 0; i < 3; ++i)
        GLOAD16(wsrc + i * 4096 + wl, wdst + i * 4096 + wu);
    }
    __builtin_amdgcn_sched_barrier(0);  // GLOADs issue before compute/stores
    const char* wb = wtb + (ch % 3) * 12288;
    f32x4 acc[2][2];
    acc[0][0] = acc[0][1] = acc[1][0] = acc[1][1] = f32x4{0.f, 0.f, 0.f, 0.f};
    if (ch < 12) {
      // swapped MFMA: D[wcol][tok]; acc[cf][tf]
      __builtin_amdgcn_s_setprio(1);
#pragma unroll
      for (int ks = 0; ks < 6; ++ks) {
        int cx = (ks * 64 + g * 16) ^ xorkey;
        short8 w0 = *(const short8*)(wb + lr * 384 + cx);
        short8 w1 = *(const short8*)(wb + (16 + lr) * 384 + cx);
        acc[0][0] = mfma16(w0, xa[0][ks], acc[0][0]);
        acc[0][1] = mfma16(w0, xa[1][ks], acc[0][1]);
        acc[1][0] = mfma16(w1, xa[0][ks], acc[1][0]);
        acc[1][1] = mfma16(w1, xa[1][ks], acc[1][1]);
      }
      __builtin_amdgcn_s_setprio(0);
      const bool isq = (ch < 6);
      short* dst = isq ? qb : kb;
      const int h = isq ? ch : ch - 6;
      const float sc = isq ? QSC : 1.0f;
      size_t base = ((size_t)b * 6 + h) * 4096;
#pragma unroll
      for (int cf = 0; cf < 2; ++cf)
#pragma unroll
        for (int tf = 0; tf < 2; ++tf) {
          int tok = rowbase + tf * 16 + lr;
          int col = cf * 16 + r4;
          int idx = isq ? col : (col ^ (((tok >> 1) & 3) << 3));
          short4e s4;
          s4[0] = f2bf(acc[cf][tf][0] * sc);
          s4[1] = f2bf(acc[cf][tf][1] * sc);
          s4[2] = f2bf(acc[cf][tf][2] * sc);
          s4[3] = f2bf(acc[cf][tf][3] * sc);
          *(short4e*)&dst[base + (size_t)tok * 32 + idx] = s4;
        }
    } else {
      // non-swapped: D[tok][wcol] -> v^T swizzled stores; acc[tf][cf]
      __builtin_amdgcn_s_setprio(1);
#pragma unroll
      for (int ks = 0; ks < 6; ++ks) {
        int cx = (ks * 64 + g * 16) ^ xorkey;
        short8 w0 = *(const short8*)(wb + lr * 384 + cx);
        short8 w1 = *(const short8*)(wb + (16 + lr) * 384 + cx);
        acc[0][0] = mfma16(xa[0][ks], w0, acc[0][0]);
        acc[0][1] = mfma16(xa[0][ks], w1, acc[0][1]);
        acc[1][0] = mfma16(xa[1][ks], w0, acc[1][0]);
        acc[1][1] = mfma16(xa[1][ks], w1, acc[1][1]);
      }
      __builtin_amdgcn_s_setprio(0);
      const int h = ch - 12;
      size_t base = ((size_t)b * 6 + h) * 4096;
#pragma unroll
      for (int tf = 0; tf < 2; ++tf)
#pragma unroll
        for (int cf = 0; cf < 2; ++cf) {
          int d = cf * 16 + lr;
          int rowpos = rowbase + tf * 16 + r4;
          short4e s4;
          s4[0] = f2bf(acc[tf][cf][0]);
          s4[1] = f2bf(acc[tf][cf][1]);
          s4[2] = f2bf(acc[tf][cf][2]);
          s4[3] = f2bf(acc[tf][cf][3]);
          *(short4e*)&vb[base + (size_t)d * 128 + (rowpos ^ ((d & 15) << 3))] = s4;
        }
    }
    if (ch < 17) {
      // drain G(ch+1); allow stores(ch-1)[4] + G(ch+2)[3] + stores(ch)[4] = 11
      __builtin_amdgcn_sched_barrier(0);
      asm volatile("s_waitcnt vmcnt(11)" ::: "memory");
      __builtin_amdgcn_s_barrier();
      __builtin_amdgcn_sched_barrier(0);
    }
  }
}

// ---------------- attn per (window,head): GLOAD k/v, q direct, 32KB LDS, 4 blk/CU ----------------
__global__ __launch_bounds__(256, 4) void attn_kernel(const short* __restrict__ qb,
                                                      const short* __restrict__ kb,
                                                      const short* __restrict__ vb,
                                                      const float* __restrict__ bmF,
                                                      char* __restrict__ outc) {
  __shared__ char sbuf[16384];   // k 8KB | v 8KB (swizzled images)
  __shared__ short p_lds[8192];  // 4 waves x 4KB P scratch
  const int bh = blockIdx.x, b = bh / 6, h = bh - b * 6;
  const short* qt = qb + (size_t)bh * 4096;
  const char* kc = (const char*)(kb + (size_t)bh * 4096);
  const char* vc = (const char*)(vb + (size_t)bh * 4096);
  const float4* bm4 = (const float4*)(bmF + ((size_t)h * 64 + (b & 63)) * 16384);
  short* outSlot = (short*)(outc + (size_t)b * 98304 + 49152);
  const int tid = threadIdx.x, wave = tid >> 6, lane = tid & 63;
  const int lr = lane & 15, g = lane >> 4, r4 = g * 4;
  const int rowbase = wave * 32;
  const int wl = wave * 1024 + lane * 16;
  const int wu = wave * 1024;

  // deep-queue stage: k,v 16KB via 4 global_load_lds per thread
  GLOAD16(kc + wl,        sbuf + wu);
  GLOAD16(kc + 4096 + wl, sbuf + 4096 + wu);
  GLOAD16(vc + wl,        sbuf + 8192 + wu);
  GLOAD16(vc + 4096 + wl, sbuf + 12288 + wu);
  // q: wave-private rows, direct global->reg (coalesced), independent of LDS
  short8 qaH[2];
  qaH[0] = *(const short8*)&qt[(rowbase + lr) * 32 + g * 8];
  qaH[1] = *(const short8*)&qt[(rowbase + 16 + lr) * 32 + g * 8];
  __syncthreads();

  const char* ksb = sbuf;
  const char* vs = sbuf + 8192;
  char* pw = (char*)p_lds + wave * 4096;
  const int kkey = ((lr >> 1) & 3) << 4;  // k-row swizzle key (krow>>1)&3 == (lr>>1)&3

#pragma unroll
  for (int rf = 0; rf < 2; ++rf) {
    // prefetch bias+mask fragments for this rf (8 x 16B)
    float4 bmv[8];
#pragma unroll
    for (int i = 0; i < 8; ++i) bmv[i] = bm4[(rf * 8 + i) * 256 + tid];
    short8 qa = qaH[rf];
    f32x4 s[8];
    __builtin_amdgcn_s_setprio(1);
#pragma unroll
    for (int cf = 0; cf < 8; ++cf) {
      int krow = cf * 16 + lr;
      short8 kf = *(const short8*)(ksb + krow * 64 + ((g * 16) ^ kkey));
      f32x4 z = {0.f, 0.f, 0.f, 0.f};
      s[cf] = mfma16(qa, kf, z);
    }
    __builtin_amdgcn_s_setprio(0);
    float inv_[4];
#pragma unroll
    for (int rg = 0; rg < 4; ++rg) {
      float4 bb0 = bmv[rg * 2];
      float4 bb1 = bmv[rg * 2 + 1];
      float p0 = exp2f(s[0][rg] + bb0.x);
      float p1 = exp2f(s[1][rg] + bb0.y);
      float p2 = exp2f(s[2][rg] + bb0.z);
      float p3 = exp2f(s[3][rg] + bb0.w);
      float p4 = exp2f(s[4][rg] + bb1.x);
      float p5 = exp2f(s[5][rg] + bb1.y);
      float p6 = exp2f(s[6][rg] + bb1.z);
      float p7 = exp2f(s[7][rg] + bb1.w);
      float sum = ((p0 + p1) + (p2 + p3)) + ((p4 + p5) + (p6 + p7));
#pragma unroll
      for (int o = 1; o < 16; o <<= 1) sum += __shfl_xor(sum, o);
      inv_[rg] = 1.0f / sum;
      int rr = r4 + rg;                 // row within this rf's 16
      int base = rr * 256 + (lr << 1);
      int swz = rr << 4;
      *(short*)(pw + ((base + 0 * 32) ^ swz)) = f2bf(p0);
      *(short*)(pw + ((base + 1 * 32) ^ swz)) = f2bf(p1);
      *(short*)(pw + ((base + 2 * 32) ^ swz)) = f2bf(p2);
      *(short*)(pw + ((base + 3 * 32) ^ swz)) = f2bf(p3);
      *(short*)(pw + ((base + 4 * 32) ^ swz)) = f2bf(p4);
      *(short*)(pw + ((base + 5 * 32) ^ swz)) = f2bf(p5);
      *(short*)(pw + ((base + 6 * 32) ^ swz)) = f2bf(p6);
      *(short*)(pw + ((base + 7 * 32) ^ swz)) = f2bf(p7);
    }
    // PV: D[qtok][d]; P (wave-private) + V from LDS, no barrier
    f32x4 o0 = {0.f, 0.f, 0.f, 0.f}, o1 = {0.f, 0.f, 0.f, 0.f};
#pragma unroll
    for (int kst = 0; kst < 4; ++kst) {
      short8 pa = *(const short8*)(pw + ((lr * 256 + kst * 64 + g * 16) ^ (lr << 4)));
      short8 vb0 = *(const short8*)(vs + ((lr * 256 + kst * 64 + g * 16) ^ ((lr & 15) << 4)));
      short8 vb1 = *(const short8*)(vs + (((16 + lr) * 256 + kst * 64 + g * 16) ^ (((16 + lr) & 15) << 4)));
      __builtin_amdgcn_s_setprio(1);
      o0 = mfma16(pa, vb0, o0);
      o1 = mfma16(pa, vb1, o1);
      __builtin_amdgcn_s_setprio(0);
    }
    // epilogue (round-6 proven scalar form)
#pragma unroll
    for (int rg = 0; rg < 4; ++rg) {
      int tok = rowbase + rf * 16 + r4 + rg;
      float iv = inv_[rg];
      outSlot[(size_t)tok * 192 + h * 32 + lr] = f2bf(o0[rg] * iv);
      outSlot[(size_t)tok * 192 + h * 32 + 16 + lr] = f2bf(o1[rg] * iv);
    }
  }
}

// ---------------- proj: ain[128][192] (bf16 in own d_out slot) @ proj_w^T + b ----------------
__global__ __launch_bounds__(256, 2) void proj_kernel(const short* __restrict__ pwbf,
                                                      const float* __restrict__ pb,
                                                      float* __restrict__ out) {
  __shared__ short at[24576];
  __shared__ short wt[2][6144];
  const int b = blockIdx.x, tid = threadIdx.x;
  const int wave = tid >> 6, lane = tid & 63;
  const int lr = lane & 15, g = lane >> 4;
  const int g16 = g * 16, r4 = g * 4;
  const int rowbase = wave * 32;
  const int xorkey = (lr & 7) << 4;
  char* atb = (char*)at;
  char* wtb = (char*)wt;

  int wsoff[3], wdoff[3];
#pragma unroll
  for (int i = 0; i < 3; ++i) {
    int idx8 = i * 256 + tid;
    int r = idx8 / 24, c = idx8 - r * 24;
    wsoff[i] = idx8 * 8;
    wdoff[i] = r * 384 + ((c * 16) ^ ((r & 7) << 4));
  }
  short8 wreg[3];
#pragma unroll
  for (int i = 0; i < 3; ++i) wreg[i] = *(const short8*)(pwbf + wsoff[i]);

  const short8* ar = (const short8*)((const char*)out + (size_t)b * 98304 + 49152);
#pragma unroll
  for (int i = 0; i < 12; ++i) {
    int idx8 = i * 256 + tid;
    int r = idx8 / 24, c = idx8 - r * 24;
    short8 v = ar[idx8];
    *(short8*)(atb + r * 384 + ((c * 16) ^ ((r & 7) << 4))) = v;
  }
#pragma unroll
  for (int i = 0; i < 3; ++i) *(short8*)(wtb + wdoff[i]) = wreg[i];
  __syncthreads();

  const int rA0 = (rowbase + lr) * 384, rA1 = rA0 + 16 * 384;
  const int wB0 = lr * 384, wB1 = wB0 + 16 * 384;

  for (int ch = 0; ch < 6; ++ch) {
    if (ch < 5) {
#pragma unroll
      for (int i = 0; i < 3; ++i)
        wreg[i] = *(const short8*)(pwbf + (ch + 1) * 6144 + wsoff[i]);
    }
    const char* wbuf = wtb + (ch & 1) * 12288;
    f32x4 acc[2][2];
    acc[0][0] = acc[0][1] = acc[1][0] = acc[1][1] = f32x4{0.f, 0.f, 0.f, 0.f};
#pragma unroll
    for (int ks = 0; ks < 6; ++ks) {
      int cx = (ks * 64 + g16) ^ xorkey;
      short8 xa0 = *(const short8*)(atb + rA0 + cx);
      short8 xa1 = *(const short8*)(atb + rA1 + cx);
      short8 wf0 = *(const short8*)(wbuf + wB0 + cx);
      short8 wf1 = *(const short8*)(wbuf + wB1 + cx);
      acc[0][0] = mfma16(xa0, wf0, acc[0][0]);
      acc[0][1] = mfma16(xa0, wf1, acc[0][1]);
      acc[1][0] = mfma16(xa1, wf0, acc[1][0]);
      acc[1][1] = mfma16(xa1, wf1, acc[1][1]);
    }
#pragma unroll
    for (int cf = 0; cf < 2; ++cf) {
      int j = ch * 32 + cf * 16 + lr;
      float bj = pb[j];
#pragma unroll
      for (int rf = 0; rf < 2; ++rf)
#pragma unroll
        for (int rg = 0; rg < 4; ++rg) {
          int tok = rowbase + rf * 16 + r4 + rg;
          out[((size_t)b * 128 + tok) * 192 + j] = acc[rf][cf][rg] + bj;
        }
    }
    if (ch < 5) {
#pragma unroll
      for (int i = 0; i < 3; ++i)
        *(short8*)(wtb + ((ch + 1) & 1) * 12288 + wdoff[i]) = wreg[i];
      __syncthreads();
    }
  }
}

extern "C" void kernel_launch(void* const* d_in, const int* in_sizes, int n_in,
                              void* d_out, int out_size, void* d_ws, size_t ws_size,
                              hipStream_t stream) {
  const float* x      = (const float*)d_in[0];
  const float* mask   = (const float*)d_in[1];
  const float* qkv_w  = (const float*)d_in[2];
  const float* proj_w = (const float*)d_in[3];
  const float* proj_b = (const float*)d_in[4];
  const float* table  = (const float*)d_in[5];
  const int*   rel    = (const int*)d_in[6];
  char* ws = (char*)d_ws;
  size_t o = 0;
  float* bmF  = (float*)(ws + o); o += 25165824;   // 384 * 16384 * 4
  short* wbf  = (short*)(ws + o); o += 221184;
  short* pwbf = (short*)(ws + o); o += 73728;
  short* qbp  = (short*)(ws + o); o += 50331648;
  short* kbp  = (short*)(ws + o); o += 50331648;
  short* vbp  = (short*)(ws + o); o += 50331648;
  float* out = (float*)d_out;

  prep_w<<<144, 256, 0, stream>>>(qkv_w, proj_w, wbf, pwbf);
  prep_bm<<<384, 256, 0, stream>>>(rel, table, mask, bmF);
  qkv_kernel<<<1024, 256, 0, stream>>>(x, wbf, qbp, kbp, vbp);
  attn_kernel<<<6144, 256, 0, stream>>>(qbp, kbp, vbp, bmF, (char*)d_out);
  proj_kernel<<<1024, 256, 0, stream>>>(pwbf, proj_b, (float*)d_out);
}